// Round 7
// baseline (14.096 us; speedup 1.0000x reference)
//
#include <hip/hip_runtime.h>

#define NOUT 4096

typedef _Float16 f16x8 __attribute__((ext_vector_type(8)));
typedef __fp16   h16x2 __attribute__((ext_vector_type(2)));
typedef __fp16   h16x4 __attribute__((ext_vector_type(4)));
typedef __fp16   h16x8 __attribute__((ext_vector_type(8)));
typedef float    f32x4 __attribute__((ext_vector_type(4)));

__device__ __forceinline__ f16x8 cat4(h16x2 a, h16x2 b, h16x2 c, h16x2 d) {
    h16x4 ab = __builtin_shufflevector(a, b, 0, 1, 2, 3);
    h16x4 cd = __builtin_shufflevector(c, d, 0, 1, 2, 3);
    h16x8 v  = __builtin_shufflevector(ab, cd, 0, 1, 2, 3, 4, 5, 6, 7);
    return __builtin_bit_cast(f16x8, v);
}

// 8 f32 -> f16 hi + f16 lo fragments (hi/lo split for accuracy)
__device__ __forceinline__ void cvtfrag(float4 p0, float4 p1, f16x8& hi, f16x8& lo) {
    h16x2 h0 = __builtin_amdgcn_cvt_pkrtz(p0.x, p0.y);
    h16x2 h1 = __builtin_amdgcn_cvt_pkrtz(p0.z, p0.w);
    h16x2 h2 = __builtin_amdgcn_cvt_pkrtz(p1.x, p1.y);
    h16x2 h3 = __builtin_amdgcn_cvt_pkrtz(p1.z, p1.w);
    h16x2 l0 = __builtin_amdgcn_cvt_pkrtz(p0.x - (float)h0[0], p0.y - (float)h0[1]);
    h16x2 l1 = __builtin_amdgcn_cvt_pkrtz(p0.z - (float)h1[0], p0.w - (float)h1[1]);
    h16x2 l2 = __builtin_amdgcn_cvt_pkrtz(p1.x - (float)h2[0], p1.y - (float)h2[1]);
    h16x2 l3 = __builtin_amdgcn_cvt_pkrtz(p1.z - (float)h3[0], p1.w - (float)h3[1]);
    hi = cat4(h0, h1, h2, h3);
    lo = cat4(l0, l1, l2, l3);
}

// corr[b,n] = (1/16384) * sum_h Eh[h,n] * sum_w Ew[w,n] * A[b,h,w]
// 128-n tile, 512 threads: wave wv owns h-rows [wv*16, wv*16+16), all 8 mf.
// MFMA 16x16x32 f16: M=n (Ew hi/lo from LDS, fragment order),
//                    N=h (A rows, hi/lo in-register from global f32), K=w.
__global__ __launch_bounds__(512, 4) void gauss_fused128_kernel(
    const float* __restrict__ act,    // [8][128][128]
    const float* __restrict__ mu,     // [4096][2]
    const float* __restrict__ sigma,  // [4096][2]
    float* __restrict__ out)          // [8][4096]
{
    __shared__ f16x8  EwLDS[32][2][64];   // [ks*8+mf][plane][lane], 64 KB
    __shared__ float4 musig[128];         // mux, muy, 0.5/sx^2, 0.5/sy^2 (2 KB)
    __shared__ float  red[8][128];        // 4 KB

    const int t    = threadIdx.x;
    const int wv   = t >> 6;        // 0..7
    const int lane = t & 63;
    const int lm   = lane & 15;
    const int lg   = lane >> 4;
    const int n0   = blockIdx.x * 128;
    const int b    = blockIdx.y;
    const float* Ab = act + b * 16384;

    // ---- latency-critical param loads FIRST (gate Ew phase & barrier) ----
    // this wave's 4 combos: c = wv*4 + i ; c -> ks = c>>3, mf = c&7
    float2 mC[4], sC[4];
    #pragma unroll
    for (int i = 0; i < 4; ++i) {
        const int c = wv * 4 + i;
        const int n = n0 + (c & 7) * 16 + lm;
        mC[i] = reinterpret_cast<const float2*>(mu)[n];
        sC[i] = reinterpret_cast<const float2*>(sigma)[n];
    }
    if (t < 128) {
        float2 m = reinterpret_cast<const float2*>(mu)[n0 + t];
        float2 s = reinterpret_cast<const float2*>(sigma)[n0 + t];
        musig[t] = make_float4(m.x, m.y, 0.5f / (s.x * s.x), 0.5f / (s.y * s.y));
    }

    // ---- A prefetch for ks=0,1 (latency hidden under Ew phase) ----
    const int h = wv * 16 + lm;
    const float* r0 = Ab + h * 128 + lg * 8;
    float4 pf[2][2];   // [slot][half]
    #pragma unroll
    for (int s = 0; s < 2; ++s) {
        pf[s][0] = *reinterpret_cast<const float4*>(r0 + s * 32);
        pf[s][1] = *reinterpret_cast<const float4*>(r0 + s * 32 + 4);
    }

    // ---- Ew -> LDS in fragment order (each value computed once per block) ----
    #pragma unroll
    for (int i = 0; i < 4; ++i) {
        const int c  = wv * 4 + i;
        const int ks = c >> 3;
        const int w0 = ks * 32 + lg * 8;
        float cc = 0.5f / (sC[i].y * sC[i].y);
        float e[8];
        #pragma unroll
        for (int j = 0; j < 8; ++j) {
            float d = (float)(w0 + j) * (1.0f / 128.0f) - mC[i].y;
            e[j] = __expf(-d * d * cc);
        }
        f16x8 hi, lo;
        cvtfrag(make_float4(e[0], e[1], e[2], e[3]),
                make_float4(e[4], e[5], e[6], e[7]), hi, lo);
        EwLDS[c][0][lane] = hi;
        EwLDS[c][1][lane] = lo;
    }
    __syncthreads();

    // ---- MFMA K-loop over w (4 k-steps of 32), 24 MFMA each ----
    f32x4 acc[8] = {};   // [mf]
    #pragma unroll
    for (int ks = 0; ks < 4; ++ks) {
        const int cur = ks & 1;
        f16x8 ah, al;
        cvtfrag(pf[cur][0], pf[cur][1], ah, al);
        if (ks < 2) {   // prefetch ks+2
            pf[cur][0] = *reinterpret_cast<const float4*>(r0 + (ks + 2) * 32);
            pf[cur][1] = *reinterpret_cast<const float4*>(r0 + (ks + 2) * 32 + 4);
        }
        #pragma unroll
        for (int mf = 0; mf < 8; ++mf) {
            f16x8 ewh = EwLDS[ks * 8 + mf][0][lane];
            f16x8 ewl = EwLDS[ks * 8 + mf][1][lane];
            acc[mf] = __builtin_amdgcn_mfma_f32_16x16x32_f16(ewh, ah, acc[mf], 0, 0, 0);
            acc[mf] = __builtin_amdgcn_mfma_f32_16x16x32_f16(ewh, al, acc[mf], 0, 0, 0);
            acc[mf] = __builtin_amdgcn_mfma_f32_16x16x32_f16(ewl, ah, acc[mf], 0, 0, 0);
        }
    }

    // ---- epilogue: fold Eh (fp32), reduce over this wave's 16 h ----
    // D layout: col(h within 16) = lane&15, row(n within 16) = 4*lg + r
    const float gh = (float)h * (1.0f / 128.0f);
    #pragma unroll
    for (int mf = 0; mf < 8; ++mf) {
        float sv[4];
        #pragma unroll
        for (int r = 0; r < 4; ++r) {
            int n = mf * 16 + 4 * lg + r;
            float4 ms = musig[n];
            float d = gh - ms.x;
            float v = __expf(-d * d * ms.z) * acc[mf][r];
            v += __shfl_xor(v, 1, 64);
            v += __shfl_xor(v, 2, 64);
            v += __shfl_xor(v, 4, 64);
            v += __shfl_xor(v, 8, 64);
            sv[r] = v;                // lanes with lm==0 hold the 16-h sum
        }
        if (lm == 0) {
            #pragma unroll
            for (int r = 0; r < 4; ++r)
                red[wv][mf * 16 + 4 * lg + r] = sv[r];
        }
    }
    __syncthreads();

    if (t < 128) {
        float s = 0.f;
        #pragma unroll
        for (int w = 0; w < 8; ++w)
            s += red[w][t];
        out[b * NOUT + n0 + t] = s * (1.0f / 16384.0f);
    }
}

extern "C" void kernel_launch(void* const* d_in, const int* in_sizes, int n_in,
                              void* d_out, int out_size, void* d_ws, size_t ws_size,
                              hipStream_t stream) {
    const float* act   = (const float*)d_in[0];
    const float* mu    = (const float*)d_in[1];
    const float* sigma = (const float*)d_in[2];
    float* out = (float*)d_out;

    dim3 grid(NOUT / 128, 8);   // (32, 8) = 256 blocks, 2/CU, 4 waves/SIMD
    gauss_fused128_kernel<<<grid, 512, 0, stream>>>(act, mu, sigma, out);
}

// Round 8
// 13.218 us; speedup vs baseline: 1.0665x; 1.0665x over previous
//
#include <hip/hip_runtime.h>

#define NOUT 4096

typedef _Float16 f16x8 __attribute__((ext_vector_type(8)));
typedef __fp16   h16x2 __attribute__((ext_vector_type(2)));
typedef __fp16   h16x4 __attribute__((ext_vector_type(4)));
typedef __fp16   h16x8 __attribute__((ext_vector_type(8)));
typedef float    f32x4 __attribute__((ext_vector_type(4)));

__device__ __forceinline__ f16x8 cat4(h16x2 a, h16x2 b, h16x2 c, h16x2 d) {
    h16x4 ab = __builtin_shufflevector(a, b, 0, 1, 2, 3);
    h16x4 cd = __builtin_shufflevector(c, d, 0, 1, 2, 3);
    h16x8 v  = __builtin_shufflevector(ab, cd, 0, 1, 2, 3, 4, 5, 6, 7);
    return __builtin_bit_cast(f16x8, v);
}

// 8 f32 -> f16 hi + f16 lo fragments (hi/lo split for accuracy)
__device__ __forceinline__ void cvtfrag(float4 p0, float4 p1, f16x8& hi, f16x8& lo) {
    h16x2 h0 = __builtin_amdgcn_cvt_pkrtz(p0.x, p0.y);
    h16x2 h1 = __builtin_amdgcn_cvt_pkrtz(p0.z, p0.w);
    h16x2 h2 = __builtin_amdgcn_cvt_pkrtz(p1.x, p1.y);
    h16x2 h3 = __builtin_amdgcn_cvt_pkrtz(p1.z, p1.w);
    h16x2 l0 = __builtin_amdgcn_cvt_pkrtz(p0.x - (float)h0[0], p0.y - (float)h0[1]);
    h16x2 l1 = __builtin_amdgcn_cvt_pkrtz(p0.z - (float)h1[0], p0.w - (float)h1[1]);
    h16x2 l2 = __builtin_amdgcn_cvt_pkrtz(p1.x - (float)h2[0], p1.y - (float)h2[1]);
    h16x2 l3 = __builtin_amdgcn_cvt_pkrtz(p1.z - (float)h3[0], p1.w - (float)h3[1]);
    hi = cat4(h0, h1, h2, h3);
    lo = cat4(l0, l1, l2, l3);
}

// corr[b,n] = (1/16384) * sum_h Eh[h,n] * sum_w Ew[w,n] * A[b,h,w]
// 64-n tile, 512 threads: wave wv owns h-rows [wv*16, wv*16+16).
// MFMA 16x16x32 f16: M=n (Ew hi/lo from LDS, fragment order),
//                    N=h (A rows, hi/lo in-register from global f32), K=w.
__global__ __launch_bounds__(512, 4) void gauss_fused64_kernel(
    const float* __restrict__ act,    // [8][128][128]
    const float* __restrict__ mu,     // [4096][2]
    const float* __restrict__ sigma,  // [4096][2]
    float* __restrict__ out)          // [8][4096]
{
    __shared__ f16x8  EwLDS[16][2][64];   // [ks*4+mf][plane][lane], 32 KB
    __shared__ float4 musig[64];          // mux, muy, 0.5/sx^2, 0.5/sy^2
    __shared__ float  red[8][64];         // 2 KB

    const int t    = threadIdx.x;
    const int wv   = t >> 6;        // 0..7
    const int lane = t & 63;
    const int lm   = lane & 15;
    const int lg   = lane >> 4;
    const int n0   = blockIdx.x * 64;
    const int b    = blockIdx.y;
    const float* Ab = act + b * 16384;

    // ---- latency-critical loads FIRST: they gate the Ew phase & barrier ----
    // combos c = 2*wv, 2*wv+1; c -> ks = c>>2, mf = c&3
    const int cA = 2 * wv, cB = 2 * wv + 1;
    float2 mA = reinterpret_cast<const float2*>(mu)[n0 + (cA & 3) * 16 + lm];
    float2 sA = reinterpret_cast<const float2*>(sigma)[n0 + (cA & 3) * 16 + lm];
    float2 mB = reinterpret_cast<const float2*>(mu)[n0 + (cB & 3) * 16 + lm];
    float2 sB = reinterpret_cast<const float2*>(sigma)[n0 + (cB & 3) * 16 + lm];
    if (t < 64) {
        float2 m = reinterpret_cast<const float2*>(mu)[n0 + t];
        float2 s = reinterpret_cast<const float2*>(sigma)[n0 + t];
        musig[t] = make_float4(m.x, m.y, 0.5f / (s.x * s.x), 0.5f / (s.y * s.y));
    }

    // ---- A prefetch for ks=0,1 (hi latency hidden under Ew phase) ----
    const int h = wv * 16 + lm;
    const float* r0 = Ab + h * 128 + lg * 8;
    float4 pf[2][2];   // [slot][half]
    #pragma unroll
    for (int s = 0; s < 2; ++s) {
        pf[s][0] = *reinterpret_cast<const float4*>(r0 + s * 32);
        pf[s][1] = *reinterpret_cast<const float4*>(r0 + s * 32 + 4);
    }

    // ---- Ew -> LDS in fragment order (each value computed once per block) ----
    #pragma unroll
    for (int i = 0; i < 2; ++i) {
        const int c  = 2 * wv + i;
        const int ks = c >> 2;
        const int w0 = ks * 32 + lg * 8;
        float2 m = i ? mB : mA;
        float2 s = i ? sB : sA;
        float cc = 0.5f / (s.y * s.y);
        float e[8];
        #pragma unroll
        for (int j = 0; j < 8; ++j) {
            float d = (float)(w0 + j) * (1.0f / 128.0f) - m.y;
            e[j] = __expf(-d * d * cc);
        }
        f16x8 hi, lo;
        cvtfrag(make_float4(e[0], e[1], e[2], e[3]),
                make_float4(e[4], e[5], e[6], e[7]), hi, lo);
        EwLDS[c][0][lane] = hi;
        EwLDS[c][1][lane] = lo;
    }
    __syncthreads();

    // ---- MFMA K-loop over w (4 k-steps of 32), 12 MFMA each ----
    f32x4 acc[4] = {};   // [mf]
    #pragma unroll
    for (int ks = 0; ks < 4; ++ks) {
        const int cur = ks & 1;
        f16x8 ah, al;
        cvtfrag(pf[cur][0], pf[cur][1], ah, al);
        if (ks < 2) {   // prefetch ks+2
            pf[cur][0] = *reinterpret_cast<const float4*>(r0 + (ks + 2) * 32);
            pf[cur][1] = *reinterpret_cast<const float4*>(r0 + (ks + 2) * 32 + 4);
        }
        #pragma unroll
        for (int mf = 0; mf < 4; ++mf) {
            f16x8 ewh = EwLDS[ks * 4 + mf][0][lane];
            f16x8 ewl = EwLDS[ks * 4 + mf][1][lane];
            acc[mf] = __builtin_amdgcn_mfma_f32_16x16x32_f16(ewh, ah, acc[mf], 0, 0, 0);
            acc[mf] = __builtin_amdgcn_mfma_f32_16x16x32_f16(ewh, al, acc[mf], 0, 0, 0);
            acc[mf] = __builtin_amdgcn_mfma_f32_16x16x32_f16(ewl, ah, acc[mf], 0, 0, 0);
        }
    }

    // ---- epilogue: fold Eh (fp32), reduce over this wave's 16 h ----
    // D layout: col(h within 16) = lane&15, row(n within 16) = 4*lg + r
    const float gh = (float)h * (1.0f / 128.0f);
    float sv[4][4];
    #pragma unroll
    for (int mf = 0; mf < 4; ++mf)
        #pragma unroll
        for (int r = 0; r < 4; ++r) {
            int n = mf * 16 + 4 * lg + r;
            float4 ms = musig[n];
            float d = gh - ms.x;
            float v = __expf(-d * d * ms.z) * acc[mf][r];
            v += __shfl_xor(v, 1, 64);
            v += __shfl_xor(v, 2, 64);
            v += __shfl_xor(v, 4, 64);
            v += __shfl_xor(v, 8, 64);
            sv[mf][r] = v;            // lanes with lm==0 hold the 16-h sum
        }
    if (lm == 0) {
        #pragma unroll
        for (int mf = 0; mf < 4; ++mf)
            #pragma unroll
            for (int r = 0; r < 4; ++r)
                red[wv][mf * 16 + 4 * lg + r] = sv[mf][r];
    }
    __syncthreads();

    if (t < 64) {
        float s = 0.f;
        #pragma unroll
        for (int w = 0; w < 8; ++w)
            s += red[w][t];
        out[b * NOUT + n0 + t] = s * (1.0f / 16384.0f);
    }
}

extern "C" void kernel_launch(void* const* d_in, const int* in_sizes, int n_in,
                              void* d_out, int out_size, void* d_ws, size_t ws_size,
                              hipStream_t stream) {
    const float* act   = (const float*)d_in[0];
    const float* mu    = (const float*)d_in[1];
    const float* sigma = (const float*)d_in[2];
    float* out = (float*)d_out;

    dim3 grid(NOUT / 64, 8);   // (64, 8) = 512 blocks, 2/CU, 4 waves/SIMD
    gauss_fused64_kernel<<<grid, 512, 0, stream>>>(act, mu, sigma, out);
}